// Round 8
// baseline (251.848 us; speedup 1.0000x reference)
//
#include <hip/hip_runtime.h>
#include <hip/hip_bf16.h>

typedef __attribute__((ext_vector_type(4))) float floatx4;
typedef __attribute__((ext_vector_type(8))) int   intx8;

#define FP8_MAX_F 448.0f
#define SCALE_EPS 1e-7f

// ------ fused pre-pass: blocks 0-1791 absmax(x); blocks 1792-2047 quantize W ------------
__global__ void k_pre(const float* __restrict__ x, unsigned* __restrict__ amax, int n4,
                      const float* __restrict__ w, int* __restrict__ wq, int nw16) {
    if (blockIdx.x < 1792) {
        __shared__ float wmax[4];
        int tid = blockIdx.x * 256 + threadIdx.x;
        int stride = 1792 * 256;
        const float4* x4 = (const float4*)x;
        float m = 0.f;
        for (int i = tid; i < n4; i += stride) {
            float4 v = x4[i];
            m = fmaxf(fmaxf(fabsf(v.x), fabsf(v.y)),
                      fmaxf(m, fmaxf(fabsf(v.z), fabsf(v.w))));
        }
        #pragma unroll
        for (int off = 32; off > 0; off >>= 1) m = fmaxf(m, __shfl_xor(m, off, 64));
        if ((threadIdx.x & 63) == 0) wmax[threadIdx.x >> 6] = m;
        __syncthreads();
        if (threadIdx.x == 0) {
            float t = fmaxf(fmaxf(wmax[0], wmax[1]), fmaxf(wmax[2], wmax[3]));
            atomicMax(amax, __float_as_uint(t));
        }
    } else {
        int tid = (blockIdx.x - 1792) * 256 + threadIdx.x;
        int stride = 256 * 256;
        const float4* x4 = (const float4*)w;
        int4* q4 = (int4*)wq;
        for (int i = tid; i < nw16; i += stride) {
            float4 v0 = x4[4*i], v1 = x4[4*i+1], v2 = x4[4*i+2], v3 = x4[4*i+3];
            int4 o;
            o.x = __builtin_amdgcn_cvt_pk_fp8_f32(v0.x, v0.y, 0, false);
            o.x = __builtin_amdgcn_cvt_pk_fp8_f32(v0.z, v0.w, o.x, true);
            o.y = __builtin_amdgcn_cvt_pk_fp8_f32(v1.x, v1.y, 0, false);
            o.y = __builtin_amdgcn_cvt_pk_fp8_f32(v1.z, v1.w, o.y, true);
            o.z = __builtin_amdgcn_cvt_pk_fp8_f32(v2.x, v2.y, 0, false);
            o.z = __builtin_amdgcn_cvt_pk_fp8_f32(v2.z, v2.w, o.z, true);
            o.w = __builtin_amdgcn_cvt_pk_fp8_f32(v3.x, v3.y, 0, false);
            o.w = __builtin_amdgcn_cvt_pk_fp8_f32(v3.z, v3.w, o.w, true);
            q4[i] = o;
        }
    }
}

// ---------------- x: f32 -> e4m3 bytes (HW RNE), scale = max(absmax/448, eps) -------------
__global__ void k_quant_x(const float* __restrict__ x, int* __restrict__ xq,
                          const unsigned* __restrict__ amax, int n16) {
    float scale = fmaxf(__uint_as_float(*amax) / FP8_MAX_F, SCALE_EPS);
    int tid = blockIdx.x * blockDim.x + threadIdx.x;
    int stride = gridDim.x * blockDim.x;
    const float4* x4 = (const float4*)x;
    int4* q4 = (int4*)xq;
    for (int i = tid; i < n16; i += stride) {
        float4 v0 = x4[4*i], v1 = x4[4*i+1], v2 = x4[4*i+2], v3 = x4[4*i+3];
        int4 o;
        o.x = __builtin_amdgcn_cvt_pk_fp8_f32(v0.x / scale, v0.y / scale, 0, false);
        o.x = __builtin_amdgcn_cvt_pk_fp8_f32(v0.z / scale, v0.w / scale, o.x, true);
        o.y = __builtin_amdgcn_cvt_pk_fp8_f32(v1.x / scale, v1.y / scale, 0, false);
        o.y = __builtin_amdgcn_cvt_pk_fp8_f32(v1.z / scale, v1.w / scale, o.y, true);
        o.z = __builtin_amdgcn_cvt_pk_fp8_f32(v2.x / scale, v2.y / scale, 0, false);
        o.z = __builtin_amdgcn_cvt_pk_fp8_f32(v2.z / scale, v2.w / scale, o.z, true);
        o.w = __builtin_amdgcn_cvt_pk_fp8_f32(v3.x / scale, v3.y / scale, 0, false);
        o.w = __builtin_amdgcn_cvt_pk_fp8_f32(v3.z / scale, v3.w / scale, o.w, true);
        q4[i] = o;
    }
}

// ================= 256x256 8-wave MX-fp8 GEMM: A direct global->reg, B via LDS ============
// C[M,N] = ws * (A[M,K]fp8 . B[N,K]fp8^T) + bias.  Slab = 128 fp8-K (one 16x16x128 step).
// A-fragments are 32 contiguous global bytes/lane -> two dwordx4 straight to VGPR (L1-served
// 4x reuse across wc-waves; A panel L2-resident). Only B round-trips LDS (DMA + c^(r&7)
// swizzle). Per slab: 16 A-loads(t) then 4 B-DMAs(t+1) -> vmcnt(4) -> barrier -> 8 ds_read
// + 32 MFMA (compiler-scheduled) -> barrier. LDS-pipe ~1000cyc < MFMA 2213cyc.
#define BM 256
#define BN 256
#define BKQ 128
#define NT 16   // K / BKQ, K = 2048 fixed

#define GLOAD(src, dst) \
    __builtin_amdgcn_global_load_lds((const __attribute__((address_space(1))) void*)(src), \
                                     (__attribute__((address_space(3))) void*)(dst), 16, 0, 0)
#define BARRIER()    asm volatile("s_barrier" ::: "memory")
#define WAIT_VM(n)   asm volatile("s_waitcnt vmcnt(" #n ")" ::: "memory")

#define LDB(dstv, base, IMM) {                           \
    int4 lo_ = *(const int4*)((base) + (IMM));           \
    int4 hi_ = *(const int4*)((base) + 16 + (IMM));      \
    dstv = (intx8){lo_.x, lo_.y, lo_.z, lo_.w, hi_.x, hi_.y, hi_.z, hi_.w}; }

#define MFMA_ROW(m, af)                                                            \
    acc[m][0] = __builtin_amdgcn_mfma_scale_f32_16x16x128_f8f6f4(                  \
        af, b0, acc[m][0], 0, 0, 0, 0x7F7F7F7F, 0, 0x7F7F7F7F);                    \
    acc[m][1] = __builtin_amdgcn_mfma_scale_f32_16x16x128_f8f6f4(                  \
        af, b1, acc[m][1], 0, 0, 0, 0x7F7F7F7F, 0, 0x7F7F7F7F);                    \
    acc[m][2] = __builtin_amdgcn_mfma_scale_f32_16x16x128_f8f6f4(                  \
        af, b2, acc[m][2], 0, 0, 0, 0x7F7F7F7F, 0, 0x7F7F7F7F);                    \
    acc[m][3] = __builtin_amdgcn_mfma_scale_f32_16x16x128_f8f6f4(                  \
        af, b3, acc[m][3], 0, 0, 0, 0x7F7F7F7F, 0, 0x7F7F7F7F);

__global__ __launch_bounds__(512, 2) void k_gemm_mx(
    const unsigned char* __restrict__ A, const unsigned char* __restrict__ B,
    const float* __restrict__ bias, const float* __restrict__ wscale,
    float* __restrict__ C, int M, int N, int K) {
    __shared__ __align__(16) unsigned char lds[65536];   // [buf:2][B 32K]

    int nwg = gridDim.x;
    int bid = blockIdx.x;
    bid = (bid & 7) * (nwg >> 3) + (bid >> 3);   // XCD swizzle (nwg % 8 == 0)
    int ntn = N / BN;
    int tm = bid / ntn, tn = bid % ntn;
    int row0 = tm * BM, col0 = tn * BN;

    int tid = (int)threadIdx.x;
    int lane = tid & 63, wid = tid >> 6;
    int wr = wid >> 2, wc = wid & 3;             // 2M x 4N waves; per-wave 128x64
    int fr = lane & 15, g = lane >> 4;

    // ---- B staging: lane's global byte offset (i-invariant swizzle) + linear LDS dest
    int srow = tid >> 3;                          // 0..63
    int sc   = (tid & 7) ^ (srow & 7);            // logical chunk col (i*64 == 0 mod 8)
    const int offB0 = (col0 + srow) * K + sc * 16;    // + i*131072 + kt
    unsigned char* dstB = lds + tid * 16;             // + i*8192 + buf*32768

    // ---- B fragment base in LDS (swizzled): r&7 == fr&7 for all fragment rows
    int c0 = (2 * g) ^ (fr & 7);
    const int bL = wc * 8192 + fr * 128 + c0 * 16;         // + n*2048, + buf*32768
    const int bH = wc * 8192 + fr * 128 + (c0 ^ 1) * 16;

    // ---- A direct: lane's 32B fragment at (row0 + wr*128 + m*16 + fr)*K + kt + g*32
    const int aBase = (row0 + wr * 128 + fr) * K + g * 32;  // + m*32768 + kt

    floatx4 acc[8][4];
    #pragma unroll
    for (int m = 0; m < 8; ++m)
        #pragma unroll
        for (int n = 0; n < 4; ++n) acc[m][n] = (floatx4)(0.f);

    // prologue: stage B slab 0 into buf0 (4 DMAs)
    GLOAD(B + offB0,          dstB);
    GLOAD(B + offB0 + 131072, dstB + 8192);
    GLOAD(B + offB0 + 262144, dstB + 16384);
    GLOAD(B + offB0 + 393216, dstB + 24576);

    for (int t = 0; t < NT; ++t) {
        const int bufo = (t & 1) << 15;
        const unsigned char* BbL = lds + bufo + bL;
        const unsigned char* BbH = lds + bufo + bH;
        unsigned char* dB = dstB + (bufo ^ 32768);
        const int kt = t * BKQ;
        const int kn = ((t + 1) & (NT - 1)) * BKQ;   // wrap keeps schedule uniform

        // ---- 16 A-loads (slab t) straight to regs; compiler tracks deps
        intx8 a0, a1, a2, a3, a4, a5, a6, a7;
        const unsigned char* Ap = A + aBase + kt;
        LDB(a0, Ap, 0)
        LDB(a1, Ap, 32768)
        LDB(a2, Ap, 65536)
        LDB(a3, Ap, 98304)
        LDB(a4, Ap, 131072)
        LDB(a5, Ap, 163840)
        LDB(a6, Ap, 196608)
        LDB(a7, Ap, 229376)

        // ---- 4 B-DMAs (slab t+1); counted vmcnt leaves exactly these in flight
        GLOAD(B + kn + offB0,          dB);
        GLOAD(B + kn + offB0 + 131072, dB + 8192);
        GLOAD(B + kn + offB0 + 262144, dB + 16384);
        GLOAD(B + kn + offB0 + 393216, dB + 24576);

        WAIT_VM(4);          // A(t) regs ready + B(t) DMA retired; B(t+1) in flight
        BARRIER();           // B(t) visible to all waves

        // ---- 8 ds_read_b128 (B frags) + 32 MFMA, compiler-interleaved
        intx8 b0, b1, b2, b3;
        {
            int4 lo0 = *(const int4*)(BbL + 0);
            int4 hi0 = *(const int4*)(BbH + 0);
            int4 lo1 = *(const int4*)(BbL + 2048);
            int4 hi1 = *(const int4*)(BbH + 2048);
            int4 lo2 = *(const int4*)(BbL + 4096);
            int4 hi2 = *(const int4*)(BbH + 4096);
            int4 lo3 = *(const int4*)(BbL + 6144);
            int4 hi3 = *(const int4*)(BbH + 6144);
            b0 = (intx8){lo0.x, lo0.y, lo0.z, lo0.w, hi0.x, hi0.y, hi0.z, hi0.w};
            b1 = (intx8){lo1.x, lo1.y, lo1.z, lo1.w, hi1.x, hi1.y, hi1.z, hi1.w};
            b2 = (intx8){lo2.x, lo2.y, lo2.z, lo2.w, hi2.x, hi2.y, hi2.z, hi2.w};
            b3 = (intx8){lo3.x, lo3.y, lo3.z, lo3.w, hi3.x, hi3.y, hi3.z, hi3.w};
        }
        __builtin_amdgcn_s_setprio(1);
        MFMA_ROW(0, a0)
        MFMA_ROW(1, a1)
        MFMA_ROW(2, a2)
        MFMA_ROW(3, a3)
        MFMA_ROW(4, a4)
        MFMA_ROW(5, a5)
        MFMA_ROW(6, a6)
        MFMA_ROW(7, a7)
        __builtin_amdgcn_s_setprio(0);
        BARRIER();           // all waves done reading buf t before t+2 DMA overwrites
    }

    WAIT_VM(0);   // drain wrap-around staging before exit

    // epilogue: C/D layout (shape-determined): col=lane&15, row=(lane>>4)*4+j
    float wsv = *wscale;
    int crow = (lane >> 4) * 4;
    int ccol = lane & 15;
    float bv[4];
    #pragma unroll
    for (int n = 0; n < 4; ++n) bv[n] = bias[col0 + wc * 64 + n * 16 + ccol];
    #pragma unroll
    for (int m = 0; m < 8; ++m) {
        int r = row0 + wr * 128 + m * 16 + crow;
        #pragma unroll
        for (int n = 0; n < 4; ++n) {
            int c = col0 + wc * 64 + n * 16 + ccol;
            #pragma unroll
            for (int j = 0; j < 4; ++j)
                C[(long)(r + j) * N + c] = acc[m][n][j] * wsv + bv[n];
        }
    }
}

extern "C" void kernel_launch(void* const* d_in, const int* in_sizes, int n_in,
                              void* d_out, int out_size, void* d_ws, size_t ws_size,
                              hipStream_t stream) {
    const float* x      = (const float*)d_in[0];
    const float* w      = (const float*)d_in[1];
    const float* wscale = (const float*)d_in[2];
    const float* bias   = (const float*)d_in[3];
    float* out = (float*)d_out;

    const int K = 2048, N = 2048;
    const int M = in_sizes[0] / K;     // 16384

    unsigned char* ws = (unsigned char*)d_ws;
    unsigned* amax = (unsigned*)ws;                          // 4 B
    int* wq = (int*)(ws + 1024);                             // N*K   = 4.2 MB fp8
    int* xq = (int*)(ws + 1024 + (size_t)N * K);             // M*K   = 33.5 MB fp8

    hipMemsetAsync(amax, 0, 4, stream);
    k_pre<<<2048, 256, 0, stream>>>(x, amax, (M * K) / 4, w, wq, (N * K) / 16);
    k_quant_x<<<2048, 256, 0, stream>>>(x, xq, amax, (M * K) / 16);

    int grid = (M / BM) * (N / BN);    // 64 * 8 = 512
    k_gemm_mx<<<grid, 512, 0, stream>>>((const unsigned char*)xq, (const unsigned char*)wq,
                                        bias, wscale, out, M, N, K);
}

// Round 9
// 157.817 us; speedup vs baseline: 1.5958x; 1.5958x over previous
//
#include <hip/hip_runtime.h>
#include <hip/hip_bf16.h>

typedef __attribute__((ext_vector_type(4))) float floatx4;
typedef __attribute__((ext_vector_type(8))) int   intx8;

#define FP8_MAX_F 448.0f
#define SCALE_EPS 1e-7f

// ------ fused pre-pass: blocks 0-1791 absmax(x); blocks 1792-2047 quantize W ------------
__global__ void k_pre(const float* __restrict__ x, unsigned* __restrict__ amax, int n4,
                      const float* __restrict__ w, int* __restrict__ wq, int nw16) {
    if (blockIdx.x < 1792) {
        __shared__ float wmax[4];
        int tid = blockIdx.x * 256 + threadIdx.x;
        int stride = 1792 * 256;
        const float4* x4 = (const float4*)x;
        float m = 0.f;
        for (int i = tid; i < n4; i += stride) {
            float4 v = x4[i];
            m = fmaxf(fmaxf(fabsf(v.x), fabsf(v.y)),
                      fmaxf(m, fmaxf(fabsf(v.z), fabsf(v.w))));
        }
        #pragma unroll
        for (int off = 32; off > 0; off >>= 1) m = fmaxf(m, __shfl_xor(m, off, 64));
        if ((threadIdx.x & 63) == 0) wmax[threadIdx.x >> 6] = m;
        __syncthreads();
        if (threadIdx.x == 0) {
            float t = fmaxf(fmaxf(wmax[0], wmax[1]), fmaxf(wmax[2], wmax[3]));
            atomicMax(amax, __float_as_uint(t));
        }
    } else {
        int tid = (blockIdx.x - 1792) * 256 + threadIdx.x;
        int stride = 256 * 256;
        const float4* x4 = (const float4*)w;
        int4* q4 = (int4*)wq;
        for (int i = tid; i < nw16; i += stride) {
            float4 v0 = x4[4*i], v1 = x4[4*i+1], v2 = x4[4*i+2], v3 = x4[4*i+3];
            int4 o;
            o.x = __builtin_amdgcn_cvt_pk_fp8_f32(v0.x, v0.y, 0, false);
            o.x = __builtin_amdgcn_cvt_pk_fp8_f32(v0.z, v0.w, o.x, true);
            o.y = __builtin_amdgcn_cvt_pk_fp8_f32(v1.x, v1.y, 0, false);
            o.y = __builtin_amdgcn_cvt_pk_fp8_f32(v1.z, v1.w, o.y, true);
            o.z = __builtin_amdgcn_cvt_pk_fp8_f32(v2.x, v2.y, 0, false);
            o.z = __builtin_amdgcn_cvt_pk_fp8_f32(v2.z, v2.w, o.z, true);
            o.w = __builtin_amdgcn_cvt_pk_fp8_f32(v3.x, v3.y, 0, false);
            o.w = __builtin_amdgcn_cvt_pk_fp8_f32(v3.z, v3.w, o.w, true);
            q4[i] = o;
        }
    }
}

// ---------------- x: f32 -> e4m3 bytes (HW RNE), scale = max(absmax/448, eps) -------------
__global__ void k_quant_x(const float* __restrict__ x, int* __restrict__ xq,
                          const unsigned* __restrict__ amax, int n16) {
    float scale = fmaxf(__uint_as_float(*amax) / FP8_MAX_F, SCALE_EPS);
    int tid = blockIdx.x * blockDim.x + threadIdx.x;
    int stride = gridDim.x * blockDim.x;
    const float4* x4 = (const float4*)x;
    int4* q4 = (int4*)xq;
    for (int i = tid; i < n16; i += stride) {
        float4 v0 = x4[4*i], v1 = x4[4*i+1], v2 = x4[4*i+2], v3 = x4[4*i+3];
        int4 o;
        o.x = __builtin_amdgcn_cvt_pk_fp8_f32(v0.x / scale, v0.y / scale, 0, false);
        o.x = __builtin_amdgcn_cvt_pk_fp8_f32(v0.z / scale, v0.w / scale, o.x, true);
        o.y = __builtin_amdgcn_cvt_pk_fp8_f32(v1.x / scale, v1.y / scale, 0, false);
        o.y = __builtin_amdgcn_cvt_pk_fp8_f32(v1.z / scale, v1.w / scale, o.y, true);
        o.z = __builtin_amdgcn_cvt_pk_fp8_f32(v2.x / scale, v2.y / scale, 0, false);
        o.z = __builtin_amdgcn_cvt_pk_fp8_f32(v2.z / scale, v2.w / scale, o.z, true);
        o.w = __builtin_amdgcn_cvt_pk_fp8_f32(v3.x / scale, v3.y / scale, 0, false);
        o.w = __builtin_amdgcn_cvt_pk_fp8_f32(v3.z / scale, v3.w / scale, o.w, true);
        q4[i] = o;
    }
}

// ================= 128x128 4-wave MX-fp8 GEMM: LDS dbuf + counted vmcnt, 2 blocks/CU ======
// C[M,N] = ws * (A[M,K]fp8 . B[N,K]fp8^T) + bias.  Slab = 128 fp8-K (one 16x16x128 step).
// r2's verified 128^2 indexing + double-buffer (64KB -> 2 blocks/CU for cross-block
// overlap) + counted vmcnt(8) once per slab (no vmcnt(0) drain at barriers).
// Compiler-scheduled body; no sched_barrier / manual lgkm (m141 lesson).
#define BM 128
#define BN 128
#define BKQ 128
#define NT 16   // K / BKQ, K = 2048 fixed

#define GLOAD(src, dst) \
    __builtin_amdgcn_global_load_lds((const __attribute__((address_space(1))) void*)(src), \
                                     (__attribute__((address_space(3))) void*)(dst), 16, 0, 0)
#define BARRIER()    asm volatile("s_barrier" ::: "memory")
#define WAIT_VM(n)   asm volatile("s_waitcnt vmcnt(" #n ")" ::: "memory")

#define LDFRAG(dstv, pL, pH, IMM) {                      \
    int4 lo_ = *(const int4*)((pL) + (IMM));             \
    int4 hi_ = *(const int4*)((pH) + (IMM));             \
    dstv = (intx8){lo_.x, lo_.y, lo_.z, lo_.w, hi_.x, hi_.y, hi_.z, hi_.w}; }

#define MFMA_ROW(m, af)                                                            \
    acc[m][0] = __builtin_amdgcn_mfma_scale_f32_16x16x128_f8f6f4(                  \
        af, b0, acc[m][0], 0, 0, 0, 0x7F7F7F7F, 0, 0x7F7F7F7F);                    \
    acc[m][1] = __builtin_amdgcn_mfma_scale_f32_16x16x128_f8f6f4(                  \
        af, b1, acc[m][1], 0, 0, 0, 0x7F7F7F7F, 0, 0x7F7F7F7F);                    \
    acc[m][2] = __builtin_amdgcn_mfma_scale_f32_16x16x128_f8f6f4(                  \
        af, b2, acc[m][2], 0, 0, 0, 0x7F7F7F7F, 0, 0x7F7F7F7F);                    \
    acc[m][3] = __builtin_amdgcn_mfma_scale_f32_16x16x128_f8f6f4(                  \
        af, b3, acc[m][3], 0, 0, 0, 0x7F7F7F7F, 0, 0x7F7F7F7F);

__global__ __launch_bounds__(256, 2) void k_gemm_mx(
    const unsigned char* __restrict__ A, const unsigned char* __restrict__ B,
    const float* __restrict__ bias, const float* __restrict__ wscale,
    float* __restrict__ C, int M, int N, int K) {
    __shared__ __align__(16) unsigned char lds[65536];   // [buf:2][A 16K | B 16K]

    int nwg = gridDim.x;
    int bid = blockIdx.x;
    bid = (bid & 7) * (nwg >> 3) + (bid >> 3);   // XCD swizzle (nwg % 8 == 0)
    int ntn = N / BN;
    int tm = bid / ntn, tn = bid % ntn;
    int row0 = tm * BM, col0 = tn * BN;

    int tid = (int)threadIdx.x;
    int lane = tid & 63;
    int wid = tid >> 6;
    int wr = wid >> 1, wc = wid & 1;             // 2x2 waves; per-wave 64x64
    int fr = lane & 15, g = lane >> 4;

    // ---- staging: phys chunk p = i*256 + tid (16B); row = p>>3, phys col = p&7;
    //      logical source col = (p&7) ^ (row&7)  (both-sides swizzle, rule #21)
    int srow = tid >> 3;                          // 0..31, + i*32
    int sc   = (tid & 7) ^ (srow & 7);            // i*32 == 0 mod 8 -> i-invariant
    const int offA0 = (row0 + srow) * K + sc * 16;    // + i*65536 + kt
    const int offB0 = (col0 + srow) * K + sc * 16;
    unsigned char* dstA = lds + tid * 16;             // + i*4096 + buf*32768
    unsigned char* dstB = dstA + 16384;

    // ---- fragment bases (r&7 == fr&7 for all fragment rows)
    int c0 = (2 * g) ^ (fr & 7);
    const int aL = (wr * 64 + fr) * 128 + c0 * 16;          // + m*2048, + buf*32768
    const int aH = (wr * 64 + fr) * 128 + (c0 ^ 1) * 16;
    const int bL = 16384 + (wc * 64 + fr) * 128 + c0 * 16;  // + n*2048
    const int bH = 16384 + (wc * 64 + fr) * 128 + (c0 ^ 1) * 16;

    floatx4 acc[4][4];
    #pragma unroll
    for (int m = 0; m < 4; ++m)
        #pragma unroll
        for (int n = 0; n < 4; ++n) acc[m][n] = (floatx4)(0.f);

    // prologue: stage slab 0 into buf0 (8 call-sites, 4KB each)
    GLOAD(A + offA0,          dstA);
    GLOAD(A + offA0 + 65536,  dstA + 4096);
    GLOAD(A + offA0 + 131072, dstA + 8192);
    GLOAD(A + offA0 + 196608, dstA + 12288);
    GLOAD(B + offB0,          dstB);
    GLOAD(B + offB0 + 65536,  dstB + 4096);
    GLOAD(B + offB0 + 131072, dstB + 8192);
    GLOAD(B + offB0 + 196608, dstB + 12288);

    for (int t = 0; t < NT; ++t) {
        const int bufo = (t & 1) << 15;
        const unsigned char* AbL = lds + bufo + aL;
        const unsigned char* AbH = lds + bufo + aH;
        const unsigned char* BbL = lds + bufo + bL;
        const unsigned char* BbH = lds + bufo + bH;
        unsigned char* dA = dstA + (bufo ^ 32768);
        unsigned char* dB = dstB + (bufo ^ 32768);
        const int kn = ((t + 1) & (NT - 1)) * BKQ;   // wrap keeps schedule uniform

        // issue slab t+1's 8 staging loads (stay in flight across the barrier)
        GLOAD(A + kn + offA0,          dA);
        GLOAD(A + kn + offA0 + 65536,  dA + 4096);
        GLOAD(A + kn + offA0 + 131072, dA + 8192);
        GLOAD(A + kn + offA0 + 196608, dA + 12288);
        GLOAD(B + kn + offB0,          dB);
        GLOAD(B + kn + offB0 + 65536,  dB + 4096);
        GLOAD(B + kn + offB0 + 131072, dB + 8192);
        GLOAD(B + kn + offB0 + 196608, dB + 12288);
        WAIT_VM(8);          // slab t's 8 retired; t+1's 8 stay in flight
        BARRIER();           // every wave's slab-t staging visible

        // body: 16 ds_read_b128 + 16 MFMA, compiler-interleaved (fine-grained lgkmcnt)
        intx8 a0, a1, a2, a3, b0, b1, b2, b3;
        LDFRAG(b0, BbL, BbH, 0)
        LDFRAG(b1, BbL, BbH, 2048)
        LDFRAG(b2, BbL, BbH, 4096)
        LDFRAG(b3, BbL, BbH, 6144)
        LDFRAG(a0, AbL, AbH, 0)
        LDFRAG(a1, AbL, AbH, 2048)
        LDFRAG(a2, AbL, AbH, 4096)
        LDFRAG(a3, AbL, AbH, 6144)
        __builtin_amdgcn_s_setprio(1);
        MFMA_ROW(0, a0)
        MFMA_ROW(1, a1)
        MFMA_ROW(2, a2)
        MFMA_ROW(3, a3)
        __builtin_amdgcn_s_setprio(0);
        BARRIER();           // all waves done reading buf t before t+2 loads overwrite it
    }

    WAIT_VM(0);   // drain wrap-around staging before exit

    // epilogue: C/D layout (shape-determined): col=lane&15, row=(lane>>4)*4+j
    float wsv = *wscale;
    int crow = g * 4;
    int ccol = fr;
    float bv[4];
    #pragma unroll
    for (int n = 0; n < 4; ++n) bv[n] = bias[col0 + wc * 64 + n * 16 + ccol];
    #pragma unroll
    for (int m = 0; m < 4; ++m) {
        int r = row0 + wr * 64 + m * 16 + crow;
        #pragma unroll
        for (int n = 0; n < 4; ++n) {
            int c = col0 + wc * 64 + n * 16 + ccol;
            #pragma unroll
            for (int j = 0; j < 4; ++j)
                C[(long)(r + j) * N + c] = acc[m][n][j] * wsv + bv[n];
        }
    }
}

extern "C" void kernel_launch(void* const* d_in, const int* in_sizes, int n_in,
                              void* d_out, int out_size, void* d_ws, size_t ws_size,
                              hipStream_t stream) {
    const float* x      = (const float*)d_in[0];
    const float* w      = (const float*)d_in[1];
    const float* wscale = (const float*)d_in[2];
    const float* bias   = (const float*)d_in[3];
    float* out = (float*)d_out;

    const int K = 2048, N = 2048;
    const int M = in_sizes[0] / K;     // 16384

    unsigned char* ws = (unsigned char*)d_ws;
    unsigned* amax = (unsigned*)ws;                          // 4 B
    int* wq = (int*)(ws + 1024);                             // N*K   = 4.2 MB fp8
    int* xq = (int*)(ws + 1024 + (size_t)N * K);             // M*K   = 33.5 MB fp8

    hipMemsetAsync(amax, 0, 4, stream);
    k_pre<<<2048, 256, 0, stream>>>(x, amax, (M * K) / 4, w, wq, (N * K) / 16);
    k_quant_x<<<2048, 256, 0, stream>>>(x, xq, amax, (M * K) / 16);

    int grid = (M / BM) * (N / BN);    // 128 * 16 = 2048
    k_gemm_mx<<<grid, 256, 0, stream>>>((const unsigned char*)xq, (const unsigned char*)wq,
                                        bias, wscale, out, M, N, K);
}

// Round 10
// 144.736 us; speedup vs baseline: 1.7400x; 1.0904x over previous
//
#include <hip/hip_runtime.h>
#include <hip/hip_bf16.h>

typedef __attribute__((ext_vector_type(4))) float floatx4;
typedef __attribute__((ext_vector_type(8))) int   intx8;

#define FP8_MAX_F 448.0f
#define SCALE_EPS 1e-7f

// ------ fused pre-pass: blocks 0-1791 absmax(x); blocks 1792-2047 quantize W ------------
__global__ void k_pre(const float* __restrict__ x, unsigned* __restrict__ amax, int n4,
                      const float* __restrict__ w, int* __restrict__ wq, int nw16) {
    if (blockIdx.x < 1792) {
        __shared__ float wmax[4];
        int tid = blockIdx.x * 256 + threadIdx.x;
        int stride = 1792 * 256;
        const float4* x4 = (const float4*)x;
        float m = 0.f;
        for (int i = tid; i < n4; i += stride) {
            float4 v = x4[i];
            m = fmaxf(fmaxf(fabsf(v.x), fabsf(v.y)),
                      fmaxf(m, fmaxf(fabsf(v.z), fabsf(v.w))));
        }
        #pragma unroll
        for (int off = 32; off > 0; off >>= 1) m = fmaxf(m, __shfl_xor(m, off, 64));
        if ((threadIdx.x & 63) == 0) wmax[threadIdx.x >> 6] = m;
        __syncthreads();
        if (threadIdx.x == 0) {
            float t = fmaxf(fmaxf(wmax[0], wmax[1]), fmaxf(wmax[2], wmax[3]));
            atomicMax(amax, __float_as_uint(t));
        }
    } else {
        int tid = (blockIdx.x - 1792) * 256 + threadIdx.x;
        int stride = 256 * 256;
        const float4* x4 = (const float4*)w;
        int4* q4 = (int4*)wq;
        for (int i = tid; i < nw16; i += stride) {
            float4 v0 = x4[4*i], v1 = x4[4*i+1], v2 = x4[4*i+2], v3 = x4[4*i+3];
            int4 o;
            o.x = __builtin_amdgcn_cvt_pk_fp8_f32(v0.x, v0.y, 0, false);
            o.x = __builtin_amdgcn_cvt_pk_fp8_f32(v0.z, v0.w, o.x, true);
            o.y = __builtin_amdgcn_cvt_pk_fp8_f32(v1.x, v1.y, 0, false);
            o.y = __builtin_amdgcn_cvt_pk_fp8_f32(v1.z, v1.w, o.y, true);
            o.z = __builtin_amdgcn_cvt_pk_fp8_f32(v2.x, v2.y, 0, false);
            o.z = __builtin_amdgcn_cvt_pk_fp8_f32(v2.z, v2.w, o.z, true);
            o.w = __builtin_amdgcn_cvt_pk_fp8_f32(v3.x, v3.y, 0, false);
            o.w = __builtin_amdgcn_cvt_pk_fp8_f32(v3.z, v3.w, o.w, true);
            q4[i] = o;
        }
    }
}

// ---------------- x: f32 -> e4m3 bytes (HW RNE), scale = max(absmax/448, eps) -------------
__global__ void k_quant_x(const float* __restrict__ x, int* __restrict__ xq,
                          const unsigned* __restrict__ amax, int n16) {
    float scale = fmaxf(__uint_as_float(*amax) / FP8_MAX_F, SCALE_EPS);
    int tid = blockIdx.x * blockDim.x + threadIdx.x;
    int stride = gridDim.x * blockDim.x;
    const float4* x4 = (const float4*)x;
    int4* q4 = (int4*)xq;
    for (int i = tid; i < n16; i += stride) {
        float4 v0 = x4[4*i], v1 = x4[4*i+1], v2 = x4[4*i+2], v3 = x4[4*i+3];
        int4 o;
        o.x = __builtin_amdgcn_cvt_pk_fp8_f32(v0.x / scale, v0.y / scale, 0, false);
        o.x = __builtin_amdgcn_cvt_pk_fp8_f32(v0.z / scale, v0.w / scale, o.x, true);
        o.y = __builtin_amdgcn_cvt_pk_fp8_f32(v1.x / scale, v1.y / scale, 0, false);
        o.y = __builtin_amdgcn_cvt_pk_fp8_f32(v1.z / scale, v1.w / scale, o.y, true);
        o.z = __builtin_amdgcn_cvt_pk_fp8_f32(v2.x / scale, v2.y / scale, 0, false);
        o.z = __builtin_amdgcn_cvt_pk_fp8_f32(v2.z / scale, v2.w / scale, o.z, true);
        o.w = __builtin_amdgcn_cvt_pk_fp8_f32(v3.x / scale, v3.y / scale, 0, false);
        o.w = __builtin_amdgcn_cvt_pk_fp8_f32(v3.z / scale, v3.w / scale, o.w, true);
        q4[i] = o;
    }
}

// ================= 128x128 MX-fp8 GEMM (r2 structure) at 4 blocks/CU =====================
// C[M,N] = ws * (A[M,K]fp8 . B[N,K]fp8^T) + bias.  Slab = 128 fp8-K (one 16x16x128 step).
// r2's verified kernel: single 32KB LDS buffer, __syncthreads-drained staging, c^(r&7)
// chunk swizzle. ONE change: __launch_bounds__(256,4) -> 16 waves/CU (4 blocks) so
// co-resident blocks hide each other's DMA-drain + barrier convoys (m114 mechanism).
#define BM 128
#define BN 128
#define BKQ 128

__global__ __launch_bounds__(256, 4) void k_gemm_mx(
    const unsigned char* __restrict__ A, const unsigned char* __restrict__ B,
    const float* __restrict__ bias, const float* __restrict__ wscale,
    float* __restrict__ C, int M, int N, int K) {
    __shared__ __align__(16) unsigned char As[BM * BKQ];   // 16 KB
    __shared__ __align__(16) unsigned char Bs[BN * BKQ];   // 16 KB

    int nwg = gridDim.x;
    int bid = blockIdx.x;
    bid = (bid & 7) * (nwg >> 3) + (bid >> 3);   // XCD swizzle (nwg % 8 == 0)
    int ntn = N / BN;
    int tm = bid / ntn, tn = bid % ntn;
    int row0 = tm * BM, col0 = tn * BN;

    int tid = (int)threadIdx.x;
    int lane = tid & 63, wid = tid >> 6;
    int wr = wid >> 1, wc = wid & 1;             // 2x2 waves; per-wave 64x64
    int fr = lane & 15, g = lane >> 4;

    // staging: inst i writes physical chunks p = i*256 + tid (16B each), linear in LDS.
    int srow = tid >> 3;        // + i*32 -> physical row
    int scol = tid & 7;         // physical chunk col

    floatx4 acc[4][4];
    #pragma unroll
    for (int m = 0; m < 4; ++m)
        #pragma unroll
        for (int n = 0; n < 4; ++n) acc[m][n] = (floatx4)(0.f);

    for (int kt = 0; kt < K; kt += BKQ) {
        __syncthreads();
        #pragma unroll
        for (int i = 0; i < 4; ++i) {
            int r = i * 32 + srow;
            int c = scol ^ (r & 7);            // inverse-swizzled source chunk
            __builtin_amdgcn_global_load_lds(
                (const __attribute__((address_space(1))) void*)(A + (size_t)(row0 + r) * K + kt + c * 16),
                (__attribute__((address_space(3))) void*)(As + i * 4096 + wid * 1024), 16, 0, 0);
        }
        #pragma unroll
        for (int i = 0; i < 4; ++i) {
            int r = i * 32 + srow;
            int c = scol ^ (r & 7);
            __builtin_amdgcn_global_load_lds(
                (const __attribute__((address_space(1))) void*)(B + (size_t)(col0 + r) * K + kt + c * 16),
                (__attribute__((address_space(3))) void*)(Bs + i * 4096 + wid * 1024), 16, 0, 0);
        }
        __syncthreads();   // compiler drains vmcnt(0) before barrier -> LDS ready

        intx8 a[4], b[4];
        #pragma unroll
        for (int m = 0; m < 4; ++m) {
            int r = wr * 64 + m * 16 + fr;
            int c0 = (2 * g)     ^ (r & 7);
            int c1 = (2 * g + 1) ^ (r & 7);
            int4 lo = *(const int4*)(As + r * 128 + c0 * 16);
            int4 hi = *(const int4*)(As + r * 128 + c1 * 16);
            a[m] = (intx8){lo.x, lo.y, lo.z, lo.w, hi.x, hi.y, hi.z, hi.w};
        }
        #pragma unroll
        for (int n = 0; n < 4; ++n) {
            int r = wc * 64 + n * 16 + fr;
            int c0 = (2 * g)     ^ (r & 7);
            int c1 = (2 * g + 1) ^ (r & 7);
            int4 lo = *(const int4*)(Bs + r * 128 + c0 * 16);
            int4 hi = *(const int4*)(Bs + r * 128 + c1 * 16);
            b[n] = (intx8){lo.x, lo.y, lo.z, lo.w, hi.x, hi.y, hi.z, hi.w};
        }
        #pragma unroll
        for (int m = 0; m < 4; ++m)
            #pragma unroll
            for (int n = 0; n < 4; ++n)
                acc[m][n] = __builtin_amdgcn_mfma_scale_f32_16x16x128_f8f6f4(
                    a[m], b[n], acc[m][n], 0, 0,           // cbsz=fp8, blgp=fp8
                    0, 0x7F7F7F7F, 0, 0x7F7F7F7F);         // E8M0 scales = 1.0
    }

    // epilogue: C/D layout (shape-determined): col=lane&15, row=(lane>>4)*4+j
    float wsv = *wscale;
    int crow = g * 4;
    int ccol = fr;
    float bv[4];
    #pragma unroll
    for (int n = 0; n < 4; ++n) bv[n] = bias[col0 + wc * 64 + n * 16 + ccol];
    #pragma unroll
    for (int m = 0; m < 4; ++m) {
        int r = row0 + wr * 64 + m * 16 + crow;
        #pragma unroll
        for (int n = 0; n < 4; ++n) {
            int c = col0 + wc * 64 + n * 16 + ccol;
            #pragma unroll
            for (int j = 0; j < 4; ++j)
                C[(long)(r + j) * N + c] = acc[m][n][j] * wsv + bv[n];
        }
    }
}

extern "C" void kernel_launch(void* const* d_in, const int* in_sizes, int n_in,
                              void* d_out, int out_size, void* d_ws, size_t ws_size,
                              hipStream_t stream) {
    const float* x      = (const float*)d_in[0];
    const float* w      = (const float*)d_in[1];
    const float* wscale = (const float*)d_in[2];
    const float* bias   = (const float*)d_in[3];
    float* out = (float*)d_out;

    const int K = 2048, N = 2048;
    const int M = in_sizes[0] / K;     // 16384

    unsigned char* ws = (unsigned char*)d_ws;
    unsigned* amax = (unsigned*)ws;                          // 4 B
    int* wq = (int*)(ws + 1024);                             // N*K   = 4.2 MB fp8
    int* xq = (int*)(ws + 1024 + (size_t)N * K);             // M*K   = 33.5 MB fp8

    hipMemsetAsync(amax, 0, 4, stream);
    k_pre<<<2048, 256, 0, stream>>>(x, amax, (M * K) / 4, w, wq, (N * K) / 16);
    k_quant_x<<<2048, 256, 0, stream>>>(x, xq, amax, (M * K) / 16);

    int grid = (M / BM) * (N / BN);    // 128 * 16 = 2048
    k_gemm_mx<<<grid, 256, 0, stream>>>((const unsigned char*)xq, (const unsigned char*)wq,
                                        bias, wscale, out, M, N, K);
}